// Round 6
// baseline (709.512 us; speedup 1.0000x reference)
//
#include <hip/hip_runtime.h>
#include <math.h>

// Problem constants
#define B_ 4
#define T_ 256
#define N_ 8
#define D_ 128
#define NH_ 4
#define HD_ 32
#define LENC_ 2
#define MLPH_ 32
#define NL_SCALE_ 0.1f

typedef __bf16 bf16;
typedef __attribute__((ext_vector_type(2))) __bf16 bf16x2;
typedef __attribute__((ext_vector_type(8))) __bf16 bf16x8;
typedef __attribute__((ext_vector_type(4))) float f32x4;

__device__ __forceinline__ float gelu_f(float x) {
    return 0.5f * x * (1.0f + erff(x * 0.7071067811865476f));
}

// Power-of-2 blockDim tree reduction. All threads must call.
__device__ __forceinline__ float block_sum(float v, float* scratch) {
    int tid = threadIdx.x;
    scratch[tid] = v;
    __syncthreads();
    for (int s = blockDim.x >> 1; s > 0; s >>= 1) {
        if (tid < s) scratch[tid] += scratch[tid + s];
        __syncthreads();
    }
    float r = scratch[0];
    __syncthreads();
    return r;
}

// ---------------------------------------------------------------------------
// Merged prep: weight pack fp32->bf16, state_emb->bf16, bias pack.
__global__ void k_prep(const float* __restrict__ eqkvW, const float* __restrict__ eoutW,
                       const float* __restrict__ eff1, const float* __restrict__ eff2,
                       const float* __restrict__ wq, const float* __restrict__ wk,
                       const float* __restrict__ wv, const float* __restrict__ wo,
                       const float* __restrict__ cff1, const float* __restrict__ cff2,
                       const float* __restrict__ mlpW2, const float* __restrict__ semb,
                       const float* __restrict__ bk, const float* __restrict__ bv,
                       bf16* __restrict__ Wpk, bf16* __restrict__ sembh,
                       float* __restrict__ bpk) {
    int i = blockIdx.x * 256 + threadIdx.x;
    if (i < 540672) {
        const float* src; int off;
        if      (i < 98304)  { src = eqkvW; off = 0; }
        else if (i < 131072) { src = eoutW; off = 98304; }
        else if (i < 196608) { src = eff1;  off = 131072; }
        else if (i < 262144) { src = eff2;  off = 196608; }
        else if (i < 278528) { src = wq;    off = 262144; }
        else if (i < 294912) { src = wk;    off = 278528; }
        else if (i < 311296) { src = wv;    off = 294912; }
        else if (i < 327680) { src = wo;    off = 311296; }
        else if (i < 458752) { src = cff1;  off = 327680; }
        else if (i < 524288) { src = cff2;  off = 458752; }
        else                 { src = mlpW2; off = 524288; }
        Wpk[i] = (bf16)src[i - off];
    } else if (i < 540672 + 1048576) {
        int j = i - 540672;
        sembh[j] = (bf16)semb[j];
    } else if (i < 540672 + 1048576 + 256) {
        int t = i - 540672 - 1048576;
        bpk[t] = (t < 128) ? bk[t] : bv[t - 128];
    }
}

// ---------------------------------------------------------------------------
// K1: b1[b,t,m], t in [0,T-1)
__global__ void k_b1(const float* __restrict__ vs, const float* __restrict__ r5,
                     const float* __restrict__ A55, const float* __restrict__ bl_bias,
                     const float* __restrict__ nlW1, const float* __restrict__ nlb1,
                     const float* __restrict__ nlW2, const float* __restrict__ nlb2,
                     float* __restrict__ b1w) {
    int idx = blockIdx.x * blockDim.x + threadIdx.x;
    if (idx >= B_ * (T_ - 1)) return;
    int b = idx / (T_ - 1), t = idx % (T_ - 1);
    float x[N_];
    for (int n = 0; n < N_; n++) x[n] = vs[(b * T_ + t) * N_ + n];
    float h[MLPH_];
    for (int j = 0; j < MLPH_; j++) {
        float a = nlb1[j];
        for (int n = 0; n < N_; n++) a += x[n] * nlW1[j * N_ + n];
        h[j] = gelu_f(a);
    }
    for (int m = 0; m < N_; m++) {
        float lin = r5[m];
        for (int n = 0; n < N_; n++) lin += x[n] * A55[m * N_ + n];
        float nl = nlb2[m];
        for (int j = 0; j < MLPH_; j++) nl += h[j] * nlW2[m * MLPH_ + j];
        b1w[idx * N_ + m] = lin + NL_SCALE_ * nl + bl_bias[m];
    }
}

// ---------------------------------------------------------------------------
// K2: residuals[b,t,n,si] for SCALES = {1,2,3,5}
__global__ void k_resid(const float* __restrict__ vs, const float* __restrict__ b1w,
                        float* __restrict__ resid) {
    int idx = blockIdx.x * blockDim.x + threadIdx.x;
    if (idx >= B_ * T_ * N_) return;
    int b = idx / (T_ * N_);
    int t = (idx / N_) % T_;
    int n = idx % N_;
    const int SC[4] = {1, 2, 3, 5};
    float lx0 = logf(fmaxf(vs[(b * T_ + t) * N_ + n], 1e-6f));
    for (int si = 0; si < 4; si++) {
        int k = SC[si];
        float r = 0.0f;
        if (t < T_ - k) {
            float lx1 = logf(fmaxf(vs[(b * T_ + t + k) * N_ + n], 1e-6f));
            float a = lx1 - lx0;
            float cmin = -2.5f * (float)k, cmax = 2.0f * (float)k;
            a = fminf(fmaxf(a, cmin), cmax);
            float bk = 0.0f;
            for (int i = 0; i < k; i++) bk += b1w[(b * (T_ - 1) + t + i) * N_ + n];
            r = a - bk;
        }
        resid[idx * 4 + si] = r;
    }
}

// ---------------------------------------------------------------------------
// K3a: per-token MLP layer1 (16 -> 128, gelu), output bf16 in (b,t,n) order.
__global__ void k_mlp1(const float* __restrict__ resid, const float* __restrict__ W1,
                       const float* __restrict__ b1, bf16* __restrict__ H1h) {
    int tok = blockIdx.x;                  // b*2048 + t*8 + n
    int d = threadIdx.x;                   // 128
    int b = tok >> 11, t = (tok >> 3) & 255, n = tok & 7;
    __shared__ float f[16];
    if (d < 16) {
        int g = d >> 2, si = d & 3;
        f[d] = (t - g >= 0) ? resid[((b * T_ + (t - g)) * N_ + n) * 4 + si] : 0.0f;
    }
    __syncthreads();
    float a = b1[d];
    const float* w = W1 + d * 16;
#pragma unroll
    for (int c = 0; c < 16; c++) a += f[c] * w[c];
    H1h[(size_t)tok * 128 + d] = (bf16)gelu_f(a);
}

// K3b: gelu(OF) -> LN -> +PE -> write X0 fp32 + bf16, transposed to xt order.
__global__ void k_mlp2(const float* __restrict__ OF, const float* __restrict__ g,
                       const float* __restrict__ be, float* __restrict__ X0,
                       bf16* __restrict__ X0h) {
    int tok = blockIdx.x;
    int d = threadIdx.x;
    int b = tok >> 11, t = (tok >> 3) & 255, n = tok & 7;
    __shared__ float scratch[128];
    float v = gelu_f(OF[(size_t)tok * 128 + d]);
    float mean = block_sum(v, scratch) * (1.0f / 128.0f);
    float dv = v - mean;
    float var = block_sum(dv * dv, scratch) * (1.0f / 128.0f);
    float y = dv * rsqrtf(var + 1e-5f) * g[d] + be[d];
    int j = d >> 1;
    float freq = expf((float)(2 * j) * (-9.210340371976184f / 128.0f));
    float ang = (float)t * freq;
    y += (d & 1) ? cosf(ang) : sinf(ang);
    size_t r = ((size_t)(b * 8 + n) * 256 + t) * 128 + d;
    X0[r] = y;
    X0h[r] = (bf16)y;
}

// ---------------------------------------------------------------------------
// MFMA GEMM: C[M x N] = act(A @ W^T + bias). A bf16 [MxK] rowmajor,
// W bf16 [NxK] rowmajor. One 16x16 C tile per wave; 4 waves/block.
// mode 0: row-major write (Cf fp32 / Ch bf16).
// mode 1 (enc QKV, N=384): scatter to Qh/Kh [sh][256][32], Vth [sh][32][256].
// mode 2 (cross Q, N=128): scatter to Qh [sh][2048][32].
// mode 3 (cross KV, N=256): scatter K->Kh [sh][2048][32], V->Vth [sh][32][2048],
//         with l = t*8+n remap from xt row order.
__global__ __launch_bounds__(256) void k_gemm(
    const bf16* __restrict__ A, const bf16* __restrict__ W,
    const float* __restrict__ bias, float* __restrict__ Cf,
    bf16* __restrict__ Ch, bf16* __restrict__ dq, bf16* __restrict__ dk,
    bf16* __restrict__ dvv, int M, int N, int K, int act, int mode) {
    int lane = threadIdx.x & 63;
    int wv = threadIdx.x >> 6;
    int wtile = blockIdx.x * 4 + wv;
    int nN = N >> 4;
    int tn = wtile % nN, tm = wtile / nN;
    if (tm >= (M >> 4)) return;
    int mrow = tm * 16 + (lane & 15);
    int nrow = tn * 16 + (lane & 15);
    int g = lane >> 4;
    const bf16x8* Ap = (const bf16x8*)(A + (size_t)mrow * K) + g;
    const bf16x8* Wp = (const bf16x8*)(W + (size_t)nrow * K) + g;
    f32x4 acc = {0.0f, 0.0f, 0.0f, 0.0f};
    int nk = K >> 5;
    for (int k = 0; k < nk; k++) {
        bf16x8 av = Ap[k * 4];
        bf16x8 bv8 = Wp[k * 4];
        acc = __builtin_amdgcn_mfma_f32_16x16x32_bf16(av, bv8, acc, 0, 0, 0);
    }
    int col = tn * 16 + (lane & 15);
    int row0 = tm * 16 + g * 4;
    float bvv = bias[col];
#pragma unroll
    for (int i = 0; i < 4; i++) {
        float v = acc[i] + bvv;
        if (act) v = gelu_f(v);
        int row = row0 + i;
        if (mode == 0) {
            if (Cf) Cf[(size_t)row * N + col] = v;
            if (Ch) Ch[(size_t)row * N + col] = (bf16)v;
        } else if (mode == 1) {
            int s = row >> 8, t = row & 255;
            int h = (col >> 5) & 3, d = col & 31;
            int sh = s * 4 + h;
            if (col < 128)      dq[((size_t)sh * 256 + t) * 32 + d] = (bf16)v;
            else if (col < 256) dk[((size_t)sh * 256 + t) * 32 + d] = (bf16)v;
            else                dvv[((size_t)sh * 32 + d) * 256 + t] = (bf16)v;
        } else if (mode == 2) {
            int b = row >> 11, ll = row & 2047;
            int h = col >> 5, d = col & 31;
            dq[((size_t)(b * 4 + h) * 2048 + ll) * 32 + d] = (bf16)v;
        } else {
            int b = row >> 11, n = (row >> 8) & 7, t = row & 255;
            int ll = t * 8 + n;
            int h = (col >> 5) & 3, d = col & 31;
            if (col < 128) dk[((size_t)(b * 4 + h) * 2048 + ll) * 32 + d] = (bf16)v;
            else           dvv[((size_t)(b * 4 + h) * 32 + d) * 2048 + ll] = (bf16)v;
        }
    }
}

// ---------------------------------------------------------------------------
// MFMA flash attention v3: wave-private, 32 queries (2 m-tiles) per wave,
// register-ring prefetch depth 2, XCD-aware sh mapping (sh = bid % NSH so
// all blocks of one (seq,head) hit the same XCD's L2).
// No running max (scores bounded << 88). grid = NSH * (Lq/128), 256 thr.
// Qh [sh][Lq][32], Kh [sh][Lk][32], Vth [sh][32][Lk] (bf16, V transposed).
// Output ATTh[((sh>>2)*Lq + q)*128 + (sh&3)*32 + d] (bf16).
__global__ __launch_bounds__(256) void k_mattn(
    const bf16* __restrict__ Qh, const bf16* __restrict__ Kh,
    const bf16* __restrict__ Vth, bf16* __restrict__ ATTh,
    int Lq, int Lk, int NSH) {
    int sh = blockIdx.x % NSH;
    int qblk = blockIdx.x / NSH;
    int wv = threadIdx.x >> 6;
    int lane = threadIdx.x & 63;
    int c = lane & 15, g = lane >> 4;
    int q0 = qblk * 128 + wv * 32;

    // P tiles, wave-private, double-buffered; rows padded to 20 dwords.
    __shared__ __align__(16) bf16x2 P_lds[2][2][4][16][20];

    bf16x8 aq0 = *(const bf16x8*)(Qh + ((size_t)sh * Lq + q0 + c) * 32 + g * 8);
    bf16x8 aq1 = *(const bf16x8*)(Qh + ((size_t)sh * Lq + q0 + 16 + c) * 32 + g * 8);
    const bf16* Kbase = Kh + (size_t)sh * Lk * 32;
    const bf16* Vbase = Vth + (size_t)sh * 32 * Lk;

    f32x4 o00 = {0, 0, 0, 0}, o01 = {0, 0, 0, 0};
    f32x4 o10 = {0, 0, 0, 0}, o11 = {0, 0, 0, 0};
    float l0[4] = {0, 0, 0, 0}, l1[4] = {0, 0, 0, 0};
    const float scale = 0.17677669529663687f;  // 1/sqrt(32)
    const f32x4 zero = {0, 0, 0, 0};

    int ntiles = Lk >> 5;                // Lk >= 64 always
    bf16x8 ka[2], kb[2], va[2], vb[2];
#pragma unroll
    for (int p = 0; p < 2; p++) {
        int k0 = p << 5;
        ka[p] = *(const bf16x8*)(Kbase + (size_t)(k0 + 2 * c) * 32 + g * 8);
        kb[p] = *(const bf16x8*)(Kbase + (size_t)(k0 + 2 * c + 1) * 32 + g * 8);
        va[p] = *(const bf16x8*)(Vbase + (size_t)c * Lk + k0 + g * 8);
        vb[p] = *(const bf16x8*)(Vbase + (size_t)(16 + c) * Lk + k0 + g * 8);
    }
    for (int t = 0; t < ntiles; t++) {
        int slot = t & 1;
        bf16x8 cka = ka[slot], ckb = kb[slot], cva = va[slot], cvb = vb[slot];
        int pf = (t + 2 < ntiles) ? t + 2 : t;
        int nk0 = pf << 5;
        ka[slot] = *(const bf16x8*)(Kbase + (size_t)(nk0 + 2 * c) * 32 + g * 8);
        kb[slot] = *(const bf16x8*)(Kbase + (size_t)(nk0 + 2 * c + 1) * 32 + g * 8);
        va[slot] = *(const bf16x8*)(Vbase + (size_t)c * Lk + nk0 + g * 8);
        vb[slot] = *(const bf16x8*)(Vbase + (size_t)(16 + c) * Lk + nk0 + g * 8);

        f32x4 s00 = __builtin_amdgcn_mfma_f32_16x16x32_bf16(aq0, cka, zero, 0, 0, 0);
        f32x4 s01 = __builtin_amdgcn_mfma_f32_16x16x32_bf16(aq0, ckb, zero, 0, 0, 0);
        f32x4 s10 = __builtin_amdgcn_mfma_f32_16x16x32_bf16(aq1, cka, zero, 0, 0, 0);
        f32x4 s11 = __builtin_amdgcn_mfma_f32_16x16x32_bf16(aq1, ckb, zero, 0, 0, 0);
#pragma unroll
        for (int r = 0; r < 4; r++) {
            float e0 = __expf(s00[r] * scale);   // (q=q0+g*4+r, key 2c)
            float e1 = __expf(s01[r] * scale);   // (q=q0+g*4+r, key 2c+1)
            l0[r] += e0 + e1;
            bf16x2 p0; p0[0] = (bf16)e0; p0[1] = (bf16)e1;
            P_lds[slot][0][wv][g * 4 + r][c] = p0;
            float f0 = __expf(s10[r] * scale);
            float f1 = __expf(s11[r] * scale);
            l1[r] += f0 + f1;
            bf16x2 p1; p1[0] = (bf16)f0; p1[1] = (bf16)f1;
            P_lds[slot][1][wv][g * 4 + r][c] = p1;
        }
        // same-wave DS ordering: reads see this wave's writes, no barrier
        bf16x8 ap0 = *(const bf16x8*)&P_lds[slot][0][wv][c][g * 4];
        bf16x8 ap1 = *(const bf16x8*)&P_lds[slot][1][wv][c][g * 4];
        o00 = __builtin_amdgcn_mfma_f32_16x16x32_bf16(ap0, cva, o00, 0, 0, 0);
        o01 = __builtin_amdgcn_mfma_f32_16x16x32_bf16(ap0, cvb, o01, 0, 0, 0);
        o10 = __builtin_amdgcn_mfma_f32_16x16x32_bf16(ap1, cva, o10, 0, 0, 0);
        o11 = __builtin_amdgcn_mfma_f32_16x16x32_bf16(ap1, cvb, o11, 0, 0, 0);
    }
    // reduce l over the 16 key-lanes (xor 1,2,4,8 stays within the c group)
#pragma unroll
    for (int r = 0; r < 4; r++) {
        float s = l0[r];
        s += __shfl_xor(s, 1); s += __shfl_xor(s, 2);
        s += __shfl_xor(s, 4); s += __shfl_xor(s, 8);
        l0[r] = 1.0f / s;
        float s2 = l1[r];
        s2 += __shfl_xor(s2, 1); s2 += __shfl_xor(s2, 2);
        s2 += __shfl_xor(s2, 4); s2 += __shfl_xor(s2, 8);
        l1[r] = 1.0f / s2;
    }
    int h = sh & 3, sb = sh >> 2;
#pragma unroll
    for (int r = 0; r < 4; r++) {
        size_t row0 = (size_t)sb * Lq + q0 + g * 4 + r;
        ATTh[row0 * 128 + h * 32 + c] = (bf16)(o00[r] * l0[r]);
        ATTh[row0 * 128 + h * 32 + 16 + c] = (bf16)(o01[r] * l0[r]);
        size_t row1 = row0 + 16;
        ATTh[row1 * 128 + h * 32 + c] = (bf16)(o10[r] * l1[r]);
        ATTh[row1 * 128 + h * 32 + 16 + c] = (bf16)(o11[r] * l1[r]);
    }
}

// ---------------------------------------------------------------------------
// Residual + LN: y = LN(xin + delta)*g + be. Writes fp32 (if xf) and bf16
// (if xh, row stride hstride). If catsrc != nullptr (cross out-proj case),
// also fills xh[tok*256 + 128 + d] from catsrc in xt order (fused k_cat).
__global__ void k_ln_res(const float* __restrict__ xin, const float* __restrict__ delta,
                         const float* __restrict__ g, const float* __restrict__ be,
                         float* __restrict__ xf, bf16* __restrict__ xh, int hstride,
                         const bf16* __restrict__ catsrc) {
    int tok = blockIdx.x;
    int d = threadIdx.x;
    __shared__ float scratch[128];
    float v = xin[(size_t)tok * 128 + d] + delta[(size_t)tok * 128 + d];
    float mean = block_sum(v, scratch) * (1.0f / 128.0f);
    float dv = v - mean;
    float var = block_sum(dv * dv, scratch) * (1.0f / 128.0f);
    float y = dv * rsqrtf(var + 1e-5f) * g[d] + be[d];
    if (xf) xf[(size_t)tok * 128 + d] = y;
    if (xh) xh[(size_t)tok * hstride + d] = (bf16)y;
    if (catsrc) {
        int b = tok >> 11, t = (tok >> 3) & 255, n = tok & 7;
        xh[(size_t)tok * 256 + 128 + d] =
            catsrc[((size_t)(b * 8 + n) * 256 + t) * 128 + d];
    }
}

// ---------------------------------------------------------------------------
extern "C" void kernel_launch(void* const* d_in, const int* in_sizes, int n_in,
                              void* d_out, int out_size, void* d_ws, size_t ws_size,
                              hipStream_t stream) {
    const float* vs       = (const float*)d_in[0];
    const float* semb     = (const float*)d_in[1];
    const float* r5       = (const float*)d_in[2];
    const float* A55      = (const float*)d_in[3];
    const float* bl_bias  = (const float*)d_in[4];
    const float* nl_W1    = (const float*)d_in[5];
    const float* nl_b1    = (const float*)d_in[6];
    const float* nl_W2    = (const float*)d_in[7];
    const float* nl_b2    = (const float*)d_in[8];
    const float* mlp_W1   = (const float*)d_in[9];
    const float* mlp_b1   = (const float*)d_in[10];
    const float* mlp_W2   = (const float*)d_in[11];
    const float* mlp_b2   = (const float*)d_in[12];
    const float* mlp_ln_g = (const float*)d_in[13];
    const float* mlp_ln_b = (const float*)d_in[14];
    const float* enc_qkv_W = (const float*)d_in[15];
    const float* enc_qkv_b = (const float*)d_in[16];
    const float* enc_out_W = (const float*)d_in[17];
    const float* enc_out_b = (const float*)d_in[18];
    const float* enc_ln1_g = (const float*)d_in[19];
    const float* enc_ln1_b = (const float*)d_in[20];
    const float* enc_ff_W1 = (const float*)d_in[21];
    const float* enc_ff_b1 = (const float*)d_in[22];
    const float* enc_ff_W2 = (const float*)d_in[23];
    const float* enc_ff_b2 = (const float*)d_in[24];
    const float* enc_ln2_g = (const float*)d_in[25];
    const float* enc_ln2_b = (const float*)d_in[26];
    const float* ca_Wq = (const float*)d_in[27];
    const float* ca_bq = (const float*)d_in[28];
    const float* ca_Wk = (const float*)d_in[29];
    const float* ca_bk = (const float*)d_in[30];
    const float* ca_Wv = (const float*)d_in[31];
    const float* ca_bv = (const float*)d_in[32];
    const float* ca_Wo = (const float*)d_in[33];
    const float* ca_bo = (const float*)d_in[34];
    const float* ca_ln1_g = (const float*)d_in[35];
    const float* ca_ln1_b = (const float*)d_in[36];
    const float* ca_ff_W1 = (const float*)d_in[37];
    const float* ca_ff_b1 = (const float*)d_in[38];
    const float* ca_ff_W2 = (const float*)d_in[39];
    const float* ca_ff_b2 = (const float*)d_in[40];
    const float* ca_ln2_g = (const float*)d_in[41];
    const float* ca_ln2_b = (const float*)d_in[42];
    float* out = (float*)d_out;

    // Workspace layout (byte offsets, 256-aligned)
    char* base = (char*)d_ws;
    float* b1w   = (float*)(base + 0);          //  32 KB
    float* resid = (float*)(base + 32768);      // 128 KB
    float* X0    = (float*)(base + 163840);     //   4 MB
    float* X1    = (float*)(base + 4358144);    //   4 MB
    char*  QKVr  = base + 8552448;              //  12 MB region
    float* OF    = (float*)(base + 21135360);   //   4 MB
    bf16*  Wpk   = (bf16*) (base + 25329664);   // 1.03 MB
    float* bpk   = (float*)(base + 26411008);   //   1 KB
    bf16*  X0h   = (bf16*) (base + 26412032);   //   2 MB
    bf16*  X1h   = (bf16*) (base + 28509184);   //   2 MB
    bf16*  sembh = (bf16*) (base + 30606336);   //   2 MB
    bf16*  ATTh  = (bf16*) (base + 32703488);   //   2 MB
    bf16*  Qh    = (bf16*)QKVr;                 //   2 MB
    bf16*  Kh    = (bf16*)(QKVr + 2097152);     //   2 MB
    bf16*  Vth   = (bf16*)(QKVr + 4194304);     //   2 MB
    bf16*  CATh  = (bf16*)QKVr;                 //   4 MB (after attn done)
    bf16*  Hh    = (bf16*)(QKVr + 4194304);     //  <=8 MB (after attn done)

    const int NTOK = B_ * T_ * N_;  // 8192

    // Prep (weights + semb cast + bias pack), one launch
    k_prep<<<dim3(6209), dim3(256), 0, stream>>>(
        enc_qkv_W, enc_out_W, enc_ff_W1, enc_ff_W2, ca_Wq, ca_Wk, ca_Wv, ca_Wo,
        ca_ff_W1, ca_ff_W2, mlp_W2, semb, ca_bk, ca_bv, Wpk, sembh, bpk);

    // Residual features + token MLP
    k_b1<<<dim3((B_ * (T_ - 1) + 63) / 64), dim3(64), 0, stream>>>(
        vs, r5, A55, bl_bias, nl_W1, nl_b1, nl_W2, nl_b2, b1w);
    k_resid<<<dim3(NTOK / 64), dim3(64), 0, stream>>>(vs, b1w, resid);
    k_mlp1<<<dim3(NTOK), dim3(128), 0, stream>>>(resid, mlp_W1, mlp_b1, (bf16*)X1h);
    k_gemm<<<dim3(1024), dim3(256), 0, stream>>>(
        (bf16*)X1h, Wpk + 524288, mlp_b2, OF, nullptr, nullptr, nullptr, nullptr,
        NTOK, 128, 128, 0, 0);
    k_mlp2<<<dim3(NTOK), dim3(128), 0, stream>>>(OF, mlp_ln_g, mlp_ln_b, X0, X0h);

    // Encoder layers (NSH=128, Lq=Lk=256 -> grid 128*2=256)
    for (int i = 0; i < LENC_; i++) {
        k_gemm<<<dim3(3072), dim3(256), 0, stream>>>(
            X0h, Wpk + i * 49152, enc_qkv_b + i * 384, nullptr, nullptr,
            Qh, Kh, Vth, NTOK, 384, 128, 0, 1);
        k_mattn<<<dim3(256), dim3(256), 0, stream>>>(Qh, Kh, Vth, ATTh, 256, 256, 128);
        k_gemm<<<dim3(1024), dim3(256), 0, stream>>>(
            ATTh, Wpk + 98304 + i * 16384, enc_out_b + i * 128, OF, nullptr,
            nullptr, nullptr, nullptr, NTOK, 128, 128, 0, 0);
        k_ln_res<<<dim3(NTOK), dim3(128), 0, stream>>>(
            X0, OF, enc_ln1_g + i * 128, enc_ln1_b + i * 128, X1, X1h, 128, nullptr);
        k_gemm<<<dim3(2048), dim3(256), 0, stream>>>(
            X1h, Wpk + 131072 + i * 32768, enc_ff_b1 + i * 256, nullptr, Hh,
            nullptr, nullptr, nullptr, NTOK, 256, 128, 1, 0);
        k_gemm<<<dim3(1024), dim3(256), 0, stream>>>(
            Hh, Wpk + 196608 + i * 32768, enc_ff_b2 + i * 128, OF, nullptr,
            nullptr, nullptr, nullptr, NTOK, 128, 256, 0, 0);
        k_ln_res<<<dim3(NTOK), dim3(128), 0, stream>>>(
            X1, OF, enc_ln2_g + i * 128, enc_ln2_b + i * 128, X0, X0h, 128, nullptr);
    }

    // Cross-attention (NSH=16, Lq=Lk=2048 -> grid 16*16=256)
    k_gemm<<<dim3(1024), dim3(256), 0, stream>>>(
        sembh, Wpk + 262144, ca_bq, nullptr, nullptr, Qh, nullptr, nullptr,
        NTOK, 128, 128, 0, 2);
    k_gemm<<<dim3(2048), dim3(256), 0, stream>>>(
        X0h, Wpk + 278528, bpk, nullptr, nullptr, nullptr, Kh, Vth,
        NTOK, 256, 128, 0, 3);
    k_mattn<<<dim3(256), dim3(256), 0, stream>>>(Qh, Kh, Vth, ATTh, 2048, 2048, 16);
    k_gemm<<<dim3(1024), dim3(256), 0, stream>>>(
        ATTh, Wpk + 311296, ca_bo, OF, nullptr, nullptr, nullptr, nullptr,
        NTOK, 128, 128, 0, 0);
    // X1 = s1; CAT[:, :128] = s1 (bf16); CAT[:, 128:256] = encoder out (fused)
    k_ln_res<<<dim3(NTOK), dim3(128), 0, stream>>>(
        semb, OF, ca_ln1_g, ca_ln1_b, X1, CATh, 256, X0h);
    k_gemm<<<dim3(4096), dim3(256), 0, stream>>>(
        CATh, Wpk + 327680, ca_ff_b1, nullptr, Hh, nullptr, nullptr, nullptr,
        NTOK, 512, 256, 1, 0);
    k_gemm<<<dim3(1024), dim3(256), 0, stream>>>(
        Hh, Wpk + 458752, ca_ff_b2, OF, nullptr, nullptr, nullptr, nullptr,
        NTOK, 128, 512, 0, 0);
    k_ln_res<<<dim3(NTOK), dim3(128), 0, stream>>>(
        X1, OF, ca_ln2_g, ca_ln2_b, out, nullptr, 128, nullptr);
}

// Round 7
// 496.668 us; speedup vs baseline: 1.4285x; 1.4285x over previous
//
#include <hip/hip_runtime.h>
#include <math.h>

// Problem constants
#define B_ 4
#define T_ 256
#define N_ 8
#define D_ 128
#define NH_ 4
#define HD_ 32
#define LENC_ 2
#define MLPH_ 32
#define NL_SCALE_ 0.1f

typedef __bf16 bf16;
typedef __attribute__((ext_vector_type(2))) __bf16 bf16x2;
typedef __attribute__((ext_vector_type(8))) __bf16 bf16x8;
typedef __attribute__((ext_vector_type(4))) float f32x4;

__device__ __forceinline__ float gelu_f(float x) {
    return 0.5f * x * (1.0f + erff(x * 0.7071067811865476f));
}

// Power-of-2 blockDim tree reduction. All threads must call.
__device__ __forceinline__ float block_sum(float v, float* scratch) {
    int tid = threadIdx.x;
    scratch[tid] = v;
    __syncthreads();
    for (int s = blockDim.x >> 1; s > 0; s >>= 1) {
        if (tid < s) scratch[tid] += scratch[tid + s];
        __syncthreads();
    }
    float r = scratch[0];
    __syncthreads();
    return r;
}

// ---------------------------------------------------------------------------
// Merged prep: weight pack fp32->bf16, state_emb->bf16, bias pack.
__global__ void k_prep(const float* __restrict__ eqkvW, const float* __restrict__ eoutW,
                       const float* __restrict__ eff1, const float* __restrict__ eff2,
                       const float* __restrict__ wq, const float* __restrict__ wk,
                       const float* __restrict__ wv, const float* __restrict__ wo,
                       const float* __restrict__ cff1, const float* __restrict__ cff2,
                       const float* __restrict__ mlpW2, const float* __restrict__ semb,
                       const float* __restrict__ bk, const float* __restrict__ bv,
                       bf16* __restrict__ Wpk, bf16* __restrict__ sembh,
                       float* __restrict__ bpk) {
    int i = blockIdx.x * 256 + threadIdx.x;
    if (i < 540672) {
        const float* src; int off;
        if      (i < 98304)  { src = eqkvW; off = 0; }
        else if (i < 131072) { src = eoutW; off = 98304; }
        else if (i < 196608) { src = eff1;  off = 131072; }
        else if (i < 262144) { src = eff2;  off = 196608; }
        else if (i < 278528) { src = wq;    off = 262144; }
        else if (i < 294912) { src = wk;    off = 278528; }
        else if (i < 311296) { src = wv;    off = 294912; }
        else if (i < 327680) { src = wo;    off = 311296; }
        else if (i < 458752) { src = cff1;  off = 327680; }
        else if (i < 524288) { src = cff2;  off = 458752; }
        else                 { src = mlpW2; off = 524288; }
        Wpk[i] = (bf16)src[i - off];
    } else if (i < 540672 + 1048576) {
        int j = i - 540672;
        sembh[j] = (bf16)semb[j];
    } else if (i < 540672 + 1048576 + 256) {
        int t = i - 540672 - 1048576;
        bpk[t] = (t < 128) ? bk[t] : bv[t - 128];
    }
}

// ---------------------------------------------------------------------------
// K1: b1[b,t,m], t in [0,T-1)
__global__ void k_b1(const float* __restrict__ vs, const float* __restrict__ r5,
                     const float* __restrict__ A55, const float* __restrict__ bl_bias,
                     const float* __restrict__ nlW1, const float* __restrict__ nlb1,
                     const float* __restrict__ nlW2, const float* __restrict__ nlb2,
                     float* __restrict__ b1w) {
    int idx = blockIdx.x * blockDim.x + threadIdx.x;
    if (idx >= B_ * (T_ - 1)) return;
    int b = idx / (T_ - 1), t = idx % (T_ - 1);
    float x[N_];
    for (int n = 0; n < N_; n++) x[n] = vs[(b * T_ + t) * N_ + n];
    float h[MLPH_];
    for (int j = 0; j < MLPH_; j++) {
        float a = nlb1[j];
        for (int n = 0; n < N_; n++) a += x[n] * nlW1[j * N_ + n];
        h[j] = gelu_f(a);
    }
    for (int m = 0; m < N_; m++) {
        float lin = r5[m];
        for (int n = 0; n < N_; n++) lin += x[n] * A55[m * N_ + n];
        float nl = nlb2[m];
        for (int j = 0; j < MLPH_; j++) nl += h[j] * nlW2[m * MLPH_ + j];
        b1w[idx * N_ + m] = lin + NL_SCALE_ * nl + bl_bias[m];
    }
}

// ---------------------------------------------------------------------------
// K2: residuals[b,t,n,si] for SCALES = {1,2,3,5}
__global__ void k_resid(const float* __restrict__ vs, const float* __restrict__ b1w,
                        float* __restrict__ resid) {
    int idx = blockIdx.x * blockDim.x + threadIdx.x;
    if (idx >= B_ * T_ * N_) return;
    int b = idx / (T_ * N_);
    int t = (idx / N_) % T_;
    int n = idx % N_;
    const int SC[4] = {1, 2, 3, 5};
    float lx0 = logf(fmaxf(vs[(b * T_ + t) * N_ + n], 1e-6f));
    for (int si = 0; si < 4; si++) {
        int k = SC[si];
        float r = 0.0f;
        if (t < T_ - k) {
            float lx1 = logf(fmaxf(vs[(b * T_ + t + k) * N_ + n], 1e-6f));
            float a = lx1 - lx0;
            float cmin = -2.5f * (float)k, cmax = 2.0f * (float)k;
            a = fminf(fmaxf(a, cmin), cmax);
            float bk = 0.0f;
            for (int i = 0; i < k; i++) bk += b1w[(b * (T_ - 1) + t + i) * N_ + n];
            r = a - bk;
        }
        resid[idx * 4 + si] = r;
    }
}

// ---------------------------------------------------------------------------
// K3a: per-token MLP layer1 (16 -> 128, gelu), output bf16 in (b,t,n) order.
__global__ void k_mlp1(const float* __restrict__ resid, const float* __restrict__ W1,
                       const float* __restrict__ b1, bf16* __restrict__ H1h) {
    int tok = blockIdx.x;                  // b*2048 + t*8 + n
    int d = threadIdx.x;                   // 128
    int b = tok >> 11, t = (tok >> 3) & 255, n = tok & 7;
    __shared__ float f[16];
    if (d < 16) {
        int g = d >> 2, si = d & 3;
        f[d] = (t - g >= 0) ? resid[((b * T_ + (t - g)) * N_ + n) * 4 + si] : 0.0f;
    }
    __syncthreads();
    float a = b1[d];
    const float* w = W1 + d * 16;
#pragma unroll
    for (int c = 0; c < 16; c++) a += f[c] * w[c];
    H1h[(size_t)tok * 128 + d] = (bf16)gelu_f(a);
}

// K3b: gelu(OF) -> LN -> +PE -> write X0 fp32 + bf16, transposed to xt order.
__global__ void k_mlp2(const float* __restrict__ OF, const float* __restrict__ g,
                       const float* __restrict__ be, float* __restrict__ X0,
                       bf16* __restrict__ X0h) {
    int tok = blockIdx.x;
    int d = threadIdx.x;
    int b = tok >> 11, t = (tok >> 3) & 255, n = tok & 7;
    __shared__ float scratch[128];
    float v = gelu_f(OF[(size_t)tok * 128 + d]);
    float mean = block_sum(v, scratch) * (1.0f / 128.0f);
    float dv = v - mean;
    float var = block_sum(dv * dv, scratch) * (1.0f / 128.0f);
    float y = dv * rsqrtf(var + 1e-5f) * g[d] + be[d];
    int j = d >> 1;
    float freq = expf((float)(2 * j) * (-9.210340371976184f / 128.0f));
    float ang = (float)t * freq;
    y += (d & 1) ? cosf(ang) : sinf(ang);
    size_t r = ((size_t)(b * 8 + n) * 256 + t) * 128 + d;
    X0[r] = y;
    X0h[r] = (bf16)y;
}

// ---------------------------------------------------------------------------
// MFMA GEMM: C[M x N] = act(A @ W^T + bias). A bf16 [MxK] rowmajor,
// W bf16 [NxK] rowmajor. One 16x16 C tile per wave; 4 waves/block.
// mode 0: row-major write (Cf fp32 / Ch bf16).
// mode 1 (enc QKV, N=384): scatter to Qh/Kh [sh][256][32], Vth [sh][32][256].
// mode 2 (cross Q, N=128): scatter to Qh [sh][2048][32].
// mode 3 (cross KV, N=256): scatter K->Kh [sh][2048][32], V->Vth [sh][32][2048],
//         with l = t*8+n remap from xt row order.
__global__ __launch_bounds__(256) void k_gemm(
    const bf16* __restrict__ A, const bf16* __restrict__ W,
    const float* __restrict__ bias, float* __restrict__ Cf,
    bf16* __restrict__ Ch, bf16* __restrict__ dq, bf16* __restrict__ dk,
    bf16* __restrict__ dvv, int M, int N, int K, int act, int mode) {
    int lane = threadIdx.x & 63;
    int wv = threadIdx.x >> 6;
    int wtile = blockIdx.x * 4 + wv;
    int nN = N >> 4;
    int tn = wtile % nN, tm = wtile / nN;
    if (tm >= (M >> 4)) return;
    int mrow = tm * 16 + (lane & 15);
    int nrow = tn * 16 + (lane & 15);
    int g = lane >> 4;
    const bf16x8* Ap = (const bf16x8*)(A + (size_t)mrow * K) + g;
    const bf16x8* Wp = (const bf16x8*)(W + (size_t)nrow * K) + g;
    f32x4 acc = {0.0f, 0.0f, 0.0f, 0.0f};
    int nk = K >> 5;
    for (int k = 0; k < nk; k++) {
        bf16x8 av = Ap[k * 4];
        bf16x8 bv8 = Wp[k * 4];
        acc = __builtin_amdgcn_mfma_f32_16x16x32_bf16(av, bv8, acc, 0, 0, 0);
    }
    int col = tn * 16 + (lane & 15);
    int row0 = tm * 16 + g * 4;
    float bvv = bias[col];
#pragma unroll
    for (int i = 0; i < 4; i++) {
        float v = acc[i] + bvv;
        if (act) v = gelu_f(v);
        int row = row0 + i;
        if (mode == 0) {
            if (Cf) Cf[(size_t)row * N + col] = v;
            if (Ch) Ch[(size_t)row * N + col] = (bf16)v;
        } else if (mode == 1) {
            int s = row >> 8, t = row & 255;
            int h = (col >> 5) & 3, d = col & 31;
            int sh = s * 4 + h;
            if (col < 128)      dq[((size_t)sh * 256 + t) * 32 + d] = (bf16)v;
            else if (col < 256) dk[((size_t)sh * 256 + t) * 32 + d] = (bf16)v;
            else                dvv[((size_t)sh * 32 + d) * 256 + t] = (bf16)v;
        } else if (mode == 2) {
            int b = row >> 11, ll = row & 2047;
            int h = col >> 5, d = col & 31;
            dq[((size_t)(b * 4 + h) * 2048 + ll) * 32 + d] = (bf16)v;
        } else {
            int b = row >> 11, n = (row >> 8) & 7, t = row & 255;
            int ll = t * 8 + n;
            int h = (col >> 5) & 3, d = col & 31;
            if (col < 128) dk[((size_t)(b * 4 + h) * 2048 + ll) * 32 + d] = (bf16)v;
            else           dvv[((size_t)(b * 4 + h) * 32 + d) * 2048 + ll] = (bf16)v;
        }
    }
}

// ---------------------------------------------------------------------------
// MFMA flash attention v4: R5 structure (16 q/wave, wave-private P in LDS,
// no barrier) + XCD swizzle (sh = bid % NSH) + STATIC 4-tile software
// pipeline (16 named bf16x8 regs, no dynamic register indexing) + optional
// split-K over keys (partials are plain sums: no running max).
// grid = NSH * nqb * NS, bid = (qblk*NS + split)*NSH + sh.
// Qh [sh][Lq][32], Kh [sh][Lk][32], Vth [sh][32][Lk] (bf16, V transposed).
// NS==1: ATTh[((sh>>2)*Lq+q)*128 + (sh&3)*32 + d]. NS>1: fp32 partial
// records {o[32], l} stride 36 at part[((split*NSH+sh)*Lq+q)*36].
__global__ __launch_bounds__(256) void k_mattn(
    const bf16* __restrict__ Qh, const bf16* __restrict__ Kh,
    const bf16* __restrict__ Vth, bf16* __restrict__ ATTh,
    float* __restrict__ part, int Lq, int Lk, int NSH, int NS) {
    int sh = blockIdx.x % NSH;
    int rest = blockIdx.x / NSH;
    int split = rest % NS;
    int qblk = rest / NS;
    int wv = threadIdx.x >> 6;
    int lane = threadIdx.x & 63;
    int c = lane & 15, g = lane >> 4;
    int q0 = qblk * 64 + wv * 16;
    int klen = Lk / NS;
    int kbeg = split * klen;

    __shared__ __align__(16) bf16x2 P_lds[2][4][16][20];

    bf16x8 aq = *(const bf16x8*)(Qh + ((size_t)sh * Lq + q0 + c) * 32 + g * 8);
    // lane-resolved stream pointers (K: +1024 elems/tile, V: +32 elems/tile)
    const bf16* Kr0 = Kh + (size_t)sh * Lk * 32 + (size_t)(kbeg + 2 * c) * 32 + g * 8;
    const bf16* Kr1 = Kr0 + 32;
    const bf16* Vr0 = Vth + (size_t)sh * 32 * Lk + (size_t)c * Lk + kbeg + g * 8;
    const bf16* Vr1 = Vr0 + (size_t)16 * Lk;

    f32x4 o0 = {0, 0, 0, 0}, o1 = {0, 0, 0, 0};
    float l[4] = {0, 0, 0, 0};
    const float scale = 0.17677669529663687f;  // 1/sqrt(32)
    const f32x4 zero = {0, 0, 0, 0};

    auto tile = [&](bf16x8 ka, bf16x8 kb, bf16x8 va, bf16x8 vb, int buf) {
        f32x4 s0 = __builtin_amdgcn_mfma_f32_16x16x32_bf16(aq, ka, zero, 0, 0, 0);
        f32x4 s1 = __builtin_amdgcn_mfma_f32_16x16x32_bf16(aq, kb, zero, 0, 0, 0);
#pragma unroll
        for (int r = 0; r < 4; r++) {
            float e0 = __expf(s0[r] * scale);   // (q=q0+g*4+r, key 2c)
            float e1 = __expf(s1[r] * scale);   // (q=q0+g*4+r, key 2c+1)
            l[r] += e0 + e1;
            bf16x2 pk; pk[0] = (bf16)e0; pk[1] = (bf16)e1;
            P_lds[buf][wv][g * 4 + r][c] = pk;
        }
        // same-wave DS ordering: read sees this wave's writes, no barrier
        bf16x8 ap = *(const bf16x8*)&P_lds[buf][wv][c][g * 4];
        o0 = __builtin_amdgcn_mfma_f32_16x16x32_bf16(ap, va, o0, 0, 0, 0);
        o1 = __builtin_amdgcn_mfma_f32_16x16x32_bf16(ap, vb, o1, 0, 0, 0);
    };

    int ntiles = klen >> 5;   // 8 (enc), 64 or 32 (cross) — multiple of 4
    // preload tiles 0..3 into 16 named registers (all-static allocation)
    bf16x8 Ak0 = *(const bf16x8*)(Kr0);
    bf16x8 Bk0 = *(const bf16x8*)(Kr1);
    bf16x8 Av0 = *(const bf16x8*)(Vr0);
    bf16x8 Bv0 = *(const bf16x8*)(Vr1);
    bf16x8 Ak1 = *(const bf16x8*)(Kr0 + 1024);
    bf16x8 Bk1 = *(const bf16x8*)(Kr1 + 1024);
    bf16x8 Av1 = *(const bf16x8*)(Vr0 + 32);
    bf16x8 Bv1 = *(const bf16x8*)(Vr1 + 32);
    bf16x8 Ak2 = *(const bf16x8*)(Kr0 + 2048);
    bf16x8 Bk2 = *(const bf16x8*)(Kr1 + 2048);
    bf16x8 Av2 = *(const bf16x8*)(Vr0 + 64);
    bf16x8 Bv2 = *(const bf16x8*)(Vr1 + 64);
    bf16x8 Ak3 = *(const bf16x8*)(Kr0 + 3072);
    bf16x8 Bk3 = *(const bf16x8*)(Kr1 + 3072);
    bf16x8 Av3 = *(const bf16x8*)(Vr0 + 96);
    bf16x8 Bv3 = *(const bf16x8*)(Vr1 + 96);

    for (int base = 0; base < ntiles; base += 4) {
        // next-body pointers (clamped at tail: redundant reload, harmless)
        int adv = (base + 4 < ntiles) ? 1 : 0;
        const bf16* nKr0 = Kr0 + adv * 4096;
        const bf16* nKr1 = Kr1 + adv * 4096;
        const bf16* nVr0 = Vr0 + adv * 128;
        const bf16* nVr1 = Vr1 + adv * 128;

        tile(Ak0, Bk0, Av0, Bv0, 0);
        tile(Ak1, Bk1, Av1, Bv1, 1);
        // reload tiles base+4, base+5 (covered by the 2 computes below)
        Ak0 = *(const bf16x8*)(nKr0);
        Bk0 = *(const bf16x8*)(nKr1);
        Av0 = *(const bf16x8*)(nVr0);
        Bv0 = *(const bf16x8*)(nVr1);
        Ak1 = *(const bf16x8*)(nKr0 + 1024);
        Bk1 = *(const bf16x8*)(nKr1 + 1024);
        Av1 = *(const bf16x8*)(nVr0 + 32);
        Bv1 = *(const bf16x8*)(nVr1 + 32);
        tile(Ak2, Bk2, Av2, Bv2, 0);
        tile(Ak3, Bk3, Av3, Bv3, 1);
        // reload tiles base+6, base+7 (covered by next body's first computes)
        Ak2 = *(const bf16x8*)(nKr0 + 2048);
        Bk2 = *(const bf16x8*)(nKr1 + 2048);
        Av2 = *(const bf16x8*)(nVr0 + 64);
        Bv2 = *(const bf16x8*)(nVr1 + 64);
        Ak3 = *(const bf16x8*)(nKr0 + 3072);
        Bk3 = *(const bf16x8*)(nKr1 + 3072);
        Av3 = *(const bf16x8*)(nVr0 + 96);
        Bv3 = *(const bf16x8*)(nVr1 + 96);
        Kr0 = nKr0; Kr1 = nKr1; Vr0 = nVr0; Vr1 = nVr1;
    }

    // reduce l over the 16 key-lanes (xor 1,2,4,8 stays within the c group)
#pragma unroll
    for (int r = 0; r < 4; r++) {
        float s = l[r];
        s += __shfl_xor(s, 1); s += __shfl_xor(s, 2);
        s += __shfl_xor(s, 4); s += __shfl_xor(s, 8);
        l[r] = s;                         // full sum (invert only if NS==1)
    }
    if (NS == 1) {
        int h = sh & 3, sb = sh >> 2;
#pragma unroll
        for (int r = 0; r < 4; r++) {
            float inv = 1.0f / l[r];
            size_t row = (size_t)sb * Lq + q0 + g * 4 + r;
            ATTh[row * 128 + h * 32 + c] = (bf16)(o0[r] * inv);
            ATTh[row * 128 + h * 32 + 16 + c] = (bf16)(o1[r] * inv);
        }
    } else {
#pragma unroll
        for (int r = 0; r < 4; r++) {
            float* rec = part +
                ((size_t)(split * NSH + sh) * Lq + q0 + g * 4 + r) * 36;
            rec[c] = o0[r];
            rec[16 + c] = o1[r];
            if (c == 0) rec[32] = l[r];
        }
    }
}

// Combine NS split-K partials (plain sums) -> bf16 attention output.
__global__ void k_comb(const float* __restrict__ part, bf16* __restrict__ ATTh,
                       int Lq, int NSH, int NS) {
    int idx = blockIdx.x * 256 + threadIdx.x;     // over NSH*Lq
    if (idx >= NSH * Lq) return;
    int sh = idx / Lq, q = idx % Lq;
    float L = 0.0f;
    float o[32];
#pragma unroll
    for (int d = 0; d < 32; d++) o[d] = 0.0f;
    for (int s = 0; s < NS; s++) {
        const float* rec = part + ((size_t)(s * NSH + sh) * Lq + q) * 36;
        L += rec[32];
#pragma unroll
        for (int j = 0; j < 8; j++) {
            float4 a = ((const float4*)rec)[j];
            o[4 * j + 0] += a.x; o[4 * j + 1] += a.y;
            o[4 * j + 2] += a.z; o[4 * j + 3] += a.w;
        }
    }
    float inv = 1.0f / L;
    int sb = sh >> 2, h = sh & 3;
    bf16x8* op = (bf16x8*)(ATTh + ((size_t)sb * Lq + q) * 128 + h * 32);
#pragma unroll
    for (int j = 0; j < 4; j++) {
        bf16x8 v;
#pragma unroll
        for (int e = 0; e < 8; e++) v[e] = (bf16)(o[8 * j + e] * inv);
        op[j] = v;
    }
}

// ---------------------------------------------------------------------------
// Residual + LN: y = LN(xin + delta)*g + be. Writes fp32 (if xf) and bf16
// (if xh, row stride hstride). If catsrc != nullptr (cross out-proj case),
// also fills xh[tok*256 + 128 + d] from catsrc in xt order (fused k_cat).
__global__ void k_ln_res(const float* __restrict__ xin, const float* __restrict__ delta,
                         const float* __restrict__ g, const float* __restrict__ be,
                         float* __restrict__ xf, bf16* __restrict__ xh, int hstride,
                         const bf16* __restrict__ catsrc) {
    int tok = blockIdx.x;
    int d = threadIdx.x;
    __shared__ float scratch[128];
    float v = xin[(size_t)tok * 128 + d] + delta[(size_t)tok * 128 + d];
    float mean = block_sum(v, scratch) * (1.0f / 128.0f);
    float dv = v - mean;
    float var = block_sum(dv * dv, scratch) * (1.0f / 128.0f);
    float y = dv * rsqrtf(var + 1e-5f) * g[d] + be[d];
    if (xf) xf[(size_t)tok * 128 + d] = y;
    if (xh) xh[(size_t)tok * hstride + d] = (bf16)y;
    if (catsrc) {
        int b = tok >> 11, t = (tok >> 3) & 255, n = tok & 7;
        xh[(size_t)tok * 256 + 128 + d] =
            catsrc[((size_t)(b * 8 + n) * 256 + t) * 128 + d];
    }
}

// ---------------------------------------------------------------------------
extern "C" void kernel_launch(void* const* d_in, const int* in_sizes, int n_in,
                              void* d_out, int out_size, void* d_ws, size_t ws_size,
                              hipStream_t stream) {
    const float* vs       = (const float*)d_in[0];
    const float* semb     = (const float*)d_in[1];
    const float* r5       = (const float*)d_in[2];
    const float* A55      = (const float*)d_in[3];
    const float* bl_bias  = (const float*)d_in[4];
    const float* nl_W1    = (const float*)d_in[5];
    const float* nl_b1    = (const float*)d_in[6];
    const float* nl_W2    = (const float*)d_in[7];
    const float* nl_b2    = (const float*)d_in[8];
    const float* mlp_W1   = (const float*)d_in[9];
    const float* mlp_b1   = (const float*)d_in[10];
    const float* mlp_W2   = (const float*)d_in[11];
    const float* mlp_b2   = (const float*)d_in[12];
    const float* mlp_ln_g = (const float*)d_in[13];
    const float* mlp_ln_b = (const float*)d_in[14];
    const float* enc_qkv_W = (const float*)d_in[15];
    const float* enc_qkv_b = (const float*)d_in[16];
    const float* enc_out_W = (const float*)d_in[17];
    const float* enc_out_b = (const float*)d_in[18];
    const float* enc_ln1_g = (const float*)d_in[19];
    const float* enc_ln1_b = (const float*)d_in[20];
    const float* enc_ff_W1 = (const float*)d_in[21];
    const float* enc_ff_b1 = (const float*)d_in[22];
    const float* enc_ff_W2 = (const float*)d_in[23];
    const float* enc_ff_b2 = (const float*)d_in[24];
    const float* enc_ln2_g = (const float*)d_in[25];
    const float* enc_ln2_b = (const float*)d_in[26];
    const float* ca_Wq = (const float*)d_in[27];
    const float* ca_bq = (const float*)d_in[28];
    const float* ca_Wk = (const float*)d_in[29];
    const float* ca_bk = (const float*)d_in[30];
    const float* ca_Wv = (const float*)d_in[31];
    const float* ca_bv = (const float*)d_in[32];
    const float* ca_Wo = (const float*)d_in[33];
    const float* ca_bo = (const float*)d_in[34];
    const float* ca_ln1_g = (const float*)d_in[35];
    const float* ca_ln1_b = (const float*)d_in[36];
    const float* ca_ff_W1 = (const float*)d_in[37];
    const float* ca_ff_b1 = (const float*)d_in[38];
    const float* ca_ff_W2 = (const float*)d_in[39];
    const float* ca_ff_b2 = (const float*)d_in[40];
    const float* ca_ln2_g = (const float*)d_in[41];
    const float* ca_ln2_b = (const float*)d_in[42];
    float* out = (float*)d_out;

    // Workspace layout (byte offsets, 256-aligned)
    char* base = (char*)d_ws;
    float* b1w   = (float*)(base + 0);          //  32 KB
    float* resid = (float*)(base + 32768);      // 128 KB
    float* X0    = (float*)(base + 163840);     //   4 MB
    float* X1    = (float*)(base + 4358144);    //   4 MB
    char*  QKVr  = base + 8552448;              //  12 MB region
    float* OF    = (float*)(base + 21135360);   //   4 MB
    bf16*  Wpk   = (bf16*) (base + 25329664);   // 1.03 MB
    float* bpk   = (float*)(base + 26411008);   //   1 KB
    bf16*  X0h   = (bf16*) (base + 26412032);   //   2 MB
    bf16*  X1h   = (bf16*) (base + 28509184);   //   2 MB
    bf16*  sembh = (bf16*) (base + 30606336);   //   2 MB
    bf16*  ATTh  = (bf16*) (base + 32703488);   //   2 MB
    float* part  = (float*)(base + 34800640);   // NS*4.72 MB (split-K partials)
    bf16*  Qh    = (bf16*)QKVr;                 //   2 MB
    bf16*  Kh    = (bf16*)(QKVr + 2097152);     //   2 MB
    bf16*  Vth   = (bf16*)(QKVr + 4194304);     //   2 MB
    bf16*  CATh  = (bf16*)QKVr;                 //   4 MB (after attn done)
    bf16*  Hh    = (bf16*)(QKVr + 4194304);     //  <=8 MB (after attn done)

    // Cross split-K factor, gated on workspace size.
    int NS = (ws_size >= 34800640ull + 2ull * 4718592ull) ? 2 : 1;

    const int NTOK = B_ * T_ * N_;  // 8192

    // Prep (weights + semb cast + bias pack), one launch
    k_prep<<<dim3(6209), dim3(256), 0, stream>>>(
        enc_qkv_W, enc_out_W, enc_ff_W1, enc_ff_W2, ca_Wq, ca_Wk, ca_Wv, ca_Wo,
        ca_ff_W1, ca_ff_W2, mlp_W2, semb, ca_bk, ca_bv, Wpk, sembh, bpk);

    // Residual features + token MLP
    k_b1<<<dim3((B_ * (T_ - 1) + 63) / 64), dim3(64), 0, stream>>>(
        vs, r5, A55, bl_bias, nl_W1, nl_b1, nl_W2, nl_b2, b1w);
    k_resid<<<dim3(NTOK / 64), dim3(64), 0, stream>>>(vs, b1w, resid);
    k_mlp1<<<dim3(NTOK), dim3(128), 0, stream>>>(resid, mlp_W1, mlp_b1, (bf16*)X1h);
    k_gemm<<<dim3(1024), dim3(256), 0, stream>>>(
        (bf16*)X1h, Wpk + 524288, mlp_b2, OF, nullptr, nullptr, nullptr, nullptr,
        NTOK, 128, 128, 0, 0);
    k_mlp2<<<dim3(NTOK), dim3(128), 0, stream>>>(OF, mlp_ln_g, mlp_ln_b, X0, X0h);

    // Encoder layers (NSH=128, Lq=Lk=256, NS=1 -> grid 128*4 = 512)
    for (int i = 0; i < LENC_; i++) {
        k_gemm<<<dim3(3072), dim3(256), 0, stream>>>(
            X0h, Wpk + i * 49152, enc_qkv_b + i * 384, nullptr, nullptr,
            Qh, Kh, Vth, NTOK, 384, 128, 0, 1);
        k_mattn<<<dim3(512), dim3(256), 0, stream>>>(
            Qh, Kh, Vth, ATTh, nullptr, 256, 256, 128, 1);
        k_gemm<<<dim3(1024), dim3(256), 0, stream>>>(
            ATTh, Wpk + 98304 + i * 16384, enc_out_b + i * 128, OF, nullptr,
            nullptr, nullptr, nullptr, NTOK, 128, 128, 0, 0);
        k_ln_res<<<dim3(NTOK), dim3(128), 0, stream>>>(
            X0, OF, enc_ln1_g + i * 128, enc_ln1_b + i * 128, X1, X1h, 128, nullptr);
        k_gemm<<<dim3(2048), dim3(256), 0, stream>>>(
            X1h, Wpk + 131072 + i * 32768, enc_ff_b1 + i * 256, nullptr, Hh,
            nullptr, nullptr, nullptr, NTOK, 256, 128, 1, 0);
        k_gemm<<<dim3(1024), dim3(256), 0, stream>>>(
            Hh, Wpk + 196608 + i * 32768, enc_ff_b2 + i * 128, OF, nullptr,
            nullptr, nullptr, nullptr, NTOK, 128, 256, 0, 0);
        k_ln_res<<<dim3(NTOK), dim3(128), 0, stream>>>(
            X1, OF, enc_ln2_g + i * 128, enc_ln2_b + i * 128, X0, X0h, 128, nullptr);
    }

    // Cross-attention (NSH=16, Lq=Lk=2048 -> grid 16*32*NS)
    k_gemm<<<dim3(1024), dim3(256), 0, stream>>>(
        sembh, Wpk + 262144, ca_bq, nullptr, nullptr, Qh, nullptr, nullptr,
        NTOK, 128, 128, 0, 2);
    k_gemm<<<dim3(2048), dim3(256), 0, stream>>>(
        X0h, Wpk + 278528, bpk, nullptr, nullptr, nullptr, Kh, Vth,
        NTOK, 256, 128, 0, 3);
    k_mattn<<<dim3(16 * 32 * NS), dim3(256), 0, stream>>>(
        Qh, Kh, Vth, ATTh, part, 2048, 2048, 16, NS);
    if (NS > 1)
        k_comb<<<dim3((16 * 2048 + 255) / 256), dim3(256), 0, stream>>>(
            part, ATTh, 2048, 16, NS);
    k_gemm<<<dim3(1024), dim3(256), 0, stream>>>(
        ATTh, Wpk + 311296, ca_bo, OF, nullptr, nullptr, nullptr, nullptr,
        NTOK, 128, 128, 0, 0);
    // X1 = s1; CAT[:, :128] = s1 (bf16); CAT[:, 128:256] = encoder out (fused)
    k_ln_res<<<dim3(NTOK), dim3(128), 0, stream>>>(
        semb, OF, ca_ln1_g, ca_ln1_b, X1, CATh, 256, X0h);
    k_gemm<<<dim3(4096), dim3(256), 0, stream>>>(
        CATh, Wpk + 327680, ca_ff_b1, nullptr, Hh, nullptr, nullptr, nullptr,
        NTOK, 512, 256, 1, 0);
    k_gemm<<<dim3(1024), dim3(256), 0, stream>>>(
        Hh, Wpk + 458752, ca_ff_b2, OF, nullptr, nullptr, nullptr, nullptr,
        NTOK, 128, 512, 0, 0);
    k_ln_res<<<dim3(NTOK), dim3(128), 0, stream>>>(
        X1, OF, ca_ln2_g, ca_ln2_b, out, nullptr, 128, nullptr);
}

// Round 8
// 433.564 us; speedup vs baseline: 1.6365x; 1.1455x over previous
//
#include <hip/hip_runtime.h>
#include <math.h>

// Problem constants
#define B_ 4
#define T_ 256
#define N_ 8
#define D_ 128
#define NH_ 4
#define HD_ 32
#define LENC_ 2
#define MLPH_ 32
#define NL_SCALE_ 0.1f

typedef __bf16 bf16;
typedef __attribute__((ext_vector_type(2))) __bf16 bf16x2;
typedef __attribute__((ext_vector_type(8))) __bf16 bf16x8;
typedef __attribute__((ext_vector_type(4))) float f32x4;

__device__ __forceinline__ float gelu_f(float x) {
    return 0.5f * x * (1.0f + erff(x * 0.7071067811865476f));
}

// ---------------------------------------------------------------------------
// Merged prep: weight pack fp32->bf16, state_emb->bf16, bias pack.
__global__ void k_prep(const float* __restrict__ eqkvW, const float* __restrict__ eoutW,
                       const float* __restrict__ eff1, const float* __restrict__ eff2,
                       const float* __restrict__ wq, const float* __restrict__ wk,
                       const float* __restrict__ wv, const float* __restrict__ wo,
                       const float* __restrict__ cff1, const float* __restrict__ cff2,
                       const float* __restrict__ mlpW2, const float* __restrict__ semb,
                       const float* __restrict__ bk, const float* __restrict__ bv,
                       bf16* __restrict__ Wpk, bf16* __restrict__ sembh,
                       float* __restrict__ bpk) {
    int i = blockIdx.x * 256 + threadIdx.x;
    if (i < 540672) {
        const float* src; int off;
        if      (i < 98304)  { src = eqkvW; off = 0; }
        else if (i < 131072) { src = eoutW; off = 98304; }
        else if (i < 196608) { src = eff1;  off = 131072; }
        else if (i < 262144) { src = eff2;  off = 196608; }
        else if (i < 278528) { src = wq;    off = 262144; }
        else if (i < 294912) { src = wk;    off = 278528; }
        else if (i < 311296) { src = wv;    off = 294912; }
        else if (i < 327680) { src = wo;    off = 311296; }
        else if (i < 458752) { src = cff1;  off = 327680; }
        else if (i < 524288) { src = cff2;  off = 458752; }
        else                 { src = mlpW2; off = 524288; }
        Wpk[i] = (bf16)src[i - off];
    } else if (i < 540672 + 1048576) {
        int j = i - 540672;
        sembh[j] = (bf16)semb[j];
    } else if (i < 540672 + 1048576 + 256) {
        int t = i - 540672 - 1048576;
        bpk[t] = (t < 128) ? bk[t] : bv[t - 128];
    }
}

// ---------------------------------------------------------------------------
// K1: b1[b,t,m], t in [0,T-1)
__global__ void k_b1(const float* __restrict__ vs, const float* __restrict__ r5,
                     const float* __restrict__ A55, const float* __restrict__ bl_bias,
                     const float* __restrict__ nlW1, const float* __restrict__ nlb1,
                     const float* __restrict__ nlW2, const float* __restrict__ nlb2,
                     float* __restrict__ b1w) {
    int idx = blockIdx.x * blockDim.x + threadIdx.x;
    if (idx >= B_ * (T_ - 1)) return;
    int b = idx / (T_ - 1), t = idx % (T_ - 1);
    float x[N_];
    for (int n = 0; n < N_; n++) x[n] = vs[(b * T_ + t) * N_ + n];
    float h[MLPH_];
    for (int j = 0; j < MLPH_; j++) {
        float a = nlb1[j];
        for (int n = 0; n < N_; n++) a += x[n] * nlW1[j * N_ + n];
        h[j] = gelu_f(a);
    }
    for (int m = 0; m < N_; m++) {
        float lin = r5[m];
        for (int n = 0; n < N_; n++) lin += x[n] * A55[m * N_ + n];
        float nl = nlb2[m];
        for (int j = 0; j < MLPH_; j++) nl += h[j] * nlW2[m * MLPH_ + j];
        b1w[idx * N_ + m] = lin + NL_SCALE_ * nl + bl_bias[m];
    }
}

// ---------------------------------------------------------------------------
// K2: residuals[b,t,n,si] for SCALES = {1,2,3,5}
__global__ void k_resid(const float* __restrict__ vs, const float* __restrict__ b1w,
                        float* __restrict__ resid) {
    int idx = blockIdx.x * blockDim.x + threadIdx.x;
    if (idx >= B_ * T_ * N_) return;
    int b = idx / (T_ * N_);
    int t = (idx / N_) % T_;
    int n = idx % N_;
    const int SC[4] = {1, 2, 3, 5};
    float lx0 = logf(fmaxf(vs[(b * T_ + t) * N_ + n], 1e-6f));
    for (int si = 0; si < 4; si++) {
        int k = SC[si];
        float r = 0.0f;
        if (t < T_ - k) {
            float lx1 = logf(fmaxf(vs[(b * T_ + t + k) * N_ + n], 1e-6f));
            float a = lx1 - lx0;
            float cmin = -2.5f * (float)k, cmax = 2.0f * (float)k;
            a = fminf(fmaxf(a, cmin), cmax);
            float bk = 0.0f;
            for (int i = 0; i < k; i++) bk += b1w[(b * (T_ - 1) + t + i) * N_ + n];
            r = a - bk;
        }
        resid[idx * 4 + si] = r;
    }
}

// ---------------------------------------------------------------------------
// K3a: per-token MLP layer1 (16 -> 128, gelu), output bf16 in (b,t,n) order.
__global__ void k_mlp1(const float* __restrict__ resid, const float* __restrict__ W1,
                       const float* __restrict__ b1, bf16* __restrict__ H1h) {
    int tok = blockIdx.x;                  // b*2048 + t*8 + n
    int d = threadIdx.x;                   // 128
    int b = tok >> 11, t = (tok >> 3) & 255, n = tok & 7;
    __shared__ float f[16];
    if (d < 16) {
        int g = d >> 2, si = d & 3;
        f[d] = (t - g >= 0) ? resid[((b * T_ + (t - g)) * N_ + n) * 4 + si] : 0.0f;
    }
    __syncthreads();
    float a = b1[d];
    const float* w = W1 + d * 16;
#pragma unroll
    for (int c = 0; c < 16; c++) a += f[c] * w[c];
    H1h[(size_t)tok * 128 + d] = (bf16)gelu_f(a);
}

// ---------------------------------------------------------------------------
// MFMA GEMM: C[M x N] = act(A @ W^T + bias). A bf16 [MxK] rowmajor,
// W bf16 [NxK] rowmajor. One 16x16 C tile per wave; 4 waves/block.
// mode 0: row-major write (Cf fp32 / Ch bf16).
// mode 1 (enc QKV, N=384): scatter to Qh/Kh [sh][256][32], Vth [sh][32][256].
// mode 2 (cross Q, N=128): scatter to Qh [sh][2048][32].
// mode 3 (cross KV, N=256): scatter K->Kh [sh][2048][32], V->Vth [sh][32][2048],
//         with l = t*8+n remap from xt row order.
__global__ __launch_bounds__(256) void k_gemm(
    const bf16* __restrict__ A, const bf16* __restrict__ W,
    const float* __restrict__ bias, float* __restrict__ Cf,
    bf16* __restrict__ Ch, bf16* __restrict__ dq, bf16* __restrict__ dk,
    bf16* __restrict__ dvv, int M, int N, int K, int act, int mode) {
    int lane = threadIdx.x & 63;
    int wv = threadIdx.x >> 6;
    int wtile = blockIdx.x * 4 + wv;
    int nN = N >> 4;
    int tn = wtile % nN, tm = wtile / nN;
    if (tm >= (M >> 4)) return;
    int mrow = tm * 16 + (lane & 15);
    int nrow = tn * 16 + (lane & 15);
    int g = lane >> 4;
    const bf16x8* Ap = (const bf16x8*)(A + (size_t)mrow * K) + g;
    const bf16x8* Wp = (const bf16x8*)(W + (size_t)nrow * K) + g;
    f32x4 acc = {0.0f, 0.0f, 0.0f, 0.0f};
    int nk = K >> 5;
    for (int k = 0; k < nk; k++) {
        bf16x8 av = Ap[k * 4];
        bf16x8 bv8 = Wp[k * 4];
        acc = __builtin_amdgcn_mfma_f32_16x16x32_bf16(av, bv8, acc, 0, 0, 0);
    }
    int col = tn * 16 + (lane & 15);
    int row0 = tm * 16 + g * 4;
    float bvv = bias[col];
#pragma unroll
    for (int i = 0; i < 4; i++) {
        float v = acc[i] + bvv;
        if (act) v = gelu_f(v);
        int row = row0 + i;
        if (mode == 0) {
            if (Cf) Cf[(size_t)row * N + col] = v;
            if (Ch) Ch[(size_t)row * N + col] = (bf16)v;
        } else if (mode == 1) {
            int s = row >> 8, t = row & 255;
            int h = (col >> 5) & 3, d = col & 31;
            int sh = s * 4 + h;
            if (col < 128)      dq[((size_t)sh * 256 + t) * 32 + d] = (bf16)v;
            else if (col < 256) dk[((size_t)sh * 256 + t) * 32 + d] = (bf16)v;
            else                dvv[((size_t)sh * 32 + d) * 256 + t] = (bf16)v;
        } else if (mode == 2) {
            int b = row >> 11, ll = row & 2047;
            int h = col >> 5, d = col & 31;
            dq[((size_t)(b * 4 + h) * 2048 + ll) * 32 + d] = (bf16)v;
        } else {
            int b = row >> 11, n = (row >> 8) & 7, t = row & 255;
            int ll = t * 8 + n;
            int h = (col >> 5) & 3, d = col & 31;
            if (col < 128) dk[((size_t)(b * 4 + h) * 2048 + ll) * 32 + d] = (bf16)v;
            else           dvv[((size_t)(b * 4 + h) * 32 + d) * 2048 + ll] = (bf16)v;
        }
    }
}

// ---------------------------------------------------------------------------
// Fused GEMM(N=128) + [gelu] + [residual] + LayerNorm + [PE] + writes.
// A bf16 [M x K] rowmajor, W bf16 [128 x K] rowmajor, bias[128].
// Block = 256 thr (4 waves) computes 32 rows x 128 cols; grid = M/32.
// Wave w: rows (w>>1)*16, cols (w&1)*64 (4 col-tiles). C staged in LDS,
// epilogue: v = [gelu](C+bias) [+ res]; y = LN(v)*g+be [+ PE]; write
// outf fp32 (stride 128) and/or outh bf16 (stride hs), row remap for mlp.
// flags: 1=gelu-before-LN, 2=add-PE-after-LN, 4=transpose-out-row (xt order).
__global__ __launch_bounds__(256) void k_gemm_ln(
    const bf16* __restrict__ A, const bf16* __restrict__ W,
    const float* __restrict__ bias, int K,
    const float* __restrict__ resf,
    const float* __restrict__ g, const float* __restrict__ be,
    float* __restrict__ outf, bf16* __restrict__ outh, int hs,
    const bf16* __restrict__ catsrc, int flags) {
    __shared__ float S[32][132];
    int tid = threadIdx.x;
    int w = tid >> 6, lane = tid & 63;
    int c = lane & 15, gq = lane >> 4;
    int r0 = blockIdx.x * 32 + (w >> 1) * 16;
    int cb = (w & 1) * 64;

    const bf16x8* Ap  = (const bf16x8*)(A + (size_t)(r0 + c) * K) + gq;
    const bf16x8* Wp0 = (const bf16x8*)(W + (size_t)(cb + c) * K) + gq;
    const bf16x8* Wp1 = (const bf16x8*)(W + (size_t)(cb + 16 + c) * K) + gq;
    const bf16x8* Wp2 = (const bf16x8*)(W + (size_t)(cb + 32 + c) * K) + gq;
    const bf16x8* Wp3 = (const bf16x8*)(W + (size_t)(cb + 48 + c) * K) + gq;
    f32x4 a0 = {0, 0, 0, 0}, a1 = {0, 0, 0, 0};
    f32x4 a2 = {0, 0, 0, 0}, a3 = {0, 0, 0, 0};
    int nk = K >> 5;
    for (int k = 0; k < nk; k++) {
        bf16x8 av = Ap[k * 4];
        a0 = __builtin_amdgcn_mfma_f32_16x16x32_bf16(av, Wp0[k * 4], a0, 0, 0, 0);
        a1 = __builtin_amdgcn_mfma_f32_16x16x32_bf16(av, Wp1[k * 4], a1, 0, 0, 0);
        a2 = __builtin_amdgcn_mfma_f32_16x16x32_bf16(av, Wp2[k * 4], a2, 0, 0, 0);
        a3 = __builtin_amdgcn_mfma_f32_16x16x32_bf16(av, Wp3[k * 4], a3, 0, 0, 0);
    }
    int lrow = (w >> 1) * 16 + gq * 4;
    float b0 = bias[cb + c], b1v = bias[cb + 16 + c];
    float b2v = bias[cb + 32 + c], b3v = bias[cb + 48 + c];
#pragma unroll
    for (int r = 0; r < 4; r++) {
        float v0 = a0[r] + b0, v1 = a1[r] + b1v;
        float v2 = a2[r] + b2v, v3 = a3[r] + b3v;
        if (flags & 1) {
            v0 = gelu_f(v0); v1 = gelu_f(v1); v2 = gelu_f(v2); v3 = gelu_f(v3);
        }
        S[lrow + r][cb + c] = v0;       S[lrow + r][cb + 16 + c] = v1;
        S[lrow + r][cb + 32 + c] = v2;  S[lrow + r][cb + 48 + c] = v3;
    }
    __syncthreads();

    int row = tid >> 3, cg = tid & 7;          // 32 rows x 8 col-groups of 16
    int grow = blockIdx.x * 32 + row;
    int b = grow >> 11, t = (grow >> 3) & 255, n = grow & 7;
    int orow = (flags & 4) ? ((b * 8 + n) * 256 + t) : grow;
    float v[16];
#pragma unroll
    for (int j = 0; j < 16; j++) v[j] = S[row][cg * 16 + j];
    if (resf) {
        const float4* rp = (const float4*)(resf + (size_t)grow * 128 + cg * 16);
#pragma unroll
        for (int j4 = 0; j4 < 4; j4++) {
            float4 rv = rp[j4];
            v[4 * j4 + 0] += rv.x; v[4 * j4 + 1] += rv.y;
            v[4 * j4 + 2] += rv.z; v[4 * j4 + 3] += rv.w;
        }
    }
    float s = 0.0f;
#pragma unroll
    for (int j = 0; j < 16; j++) s += v[j];
    s += __shfl_xor(s, 1); s += __shfl_xor(s, 2); s += __shfl_xor(s, 4);
    float mean = s * (1.0f / 128.0f);
    float vs = 0.0f;
#pragma unroll
    for (int j = 0; j < 16; j++) { float d = v[j] - mean; vs += d * d; }
    vs += __shfl_xor(vs, 1); vs += __shfl_xor(vs, 2); vs += __shfl_xor(vs, 4);
    float rstd = rsqrtf(vs * (1.0f / 128.0f) + 1e-5f);
    float y[16];
#pragma unroll
    for (int j = 0; j < 16; j++) {
        int col = cg * 16 + j;
        y[j] = (v[j] - mean) * rstd * g[col] + be[col];
    }
    if (flags & 2) {                    // sinusoidal PE, added after LN
#pragma unroll
        for (int jj = 0; jj < 8; jj++) {
            int j2 = cg * 8 + jj;       // pair index = col>>1
            float freq = expf((float)(2 * j2) * (-9.210340371976184f / 128.0f));
            float ang = (float)t * freq;
            y[2 * jj] += sinf(ang);
            y[2 * jj + 1] += cosf(ang);
        }
    }
    if (outf) {
        float4* op = (float4*)(outf + (size_t)orow * 128 + cg * 16);
#pragma unroll
        for (int j4 = 0; j4 < 4; j4++) {
            float4 o; o.x = y[4 * j4]; o.y = y[4 * j4 + 1];
            o.z = y[4 * j4 + 2]; o.w = y[4 * j4 + 3];
            op[j4] = o;
        }
    }
    if (outh) {
        bf16x8* op = (bf16x8*)(outh + (size_t)orow * hs + cg * 16);
#pragma unroll
        for (int j8 = 0; j8 < 2; j8++) {
            bf16x8 o;
#pragma unroll
            for (int e = 0; e < 8; e++) o[e] = (bf16)y[8 * j8 + e];
            op[j8] = o;
        }
        if (catsrc) {                   // fill CAT[:,128:256] from xt order
            const bf16x8* cp = (const bf16x8*)(
                catsrc + ((size_t)(b * 8 + n) * 256 + t) * 128 + cg * 16);
            bf16x8* dp = (bf16x8*)(outh + (size_t)orow * 256 + 128 + cg * 16);
            dp[0] = cp[0]; dp[1] = cp[1];
        }
    }
}

// ---------------------------------------------------------------------------
// MFMA flash attention (R5-proven): wave-private (no barriers), prefetch-1,
// packed LDS P writes. Wave = 16 queries; 32-key tiles with interleaved key
// loads (lane c handles keys 2c, 2c+1). No running max (scores bounded).
// grid = NSH * (Lq/64). Qh [sh][Lq][32], Kh [sh][Lk][32], Vth [sh][32][Lk].
// Output ATTh[((sh>>2)*Lq + q)*128 + (sh&3)*32 + d] (bf16).
__global__ __launch_bounds__(256) void k_mattn(
    const bf16* __restrict__ Qh, const bf16* __restrict__ Kh,
    const bf16* __restrict__ Vth, bf16* __restrict__ ATTh, int Lq, int Lk) {
    int nqb = Lq >> 6;
    int qblk = blockIdx.x % nqb;
    int sh = blockIdx.x / nqb;
    int wv = threadIdx.x >> 6;
    int lane = threadIdx.x & 63;
    int c = lane & 15, g = lane >> 4;
    int q0 = qblk * 64 + wv * 16;

    __shared__ __align__(16) bf16x2 P_lds[2][4][16][20];

    bf16x8 aq = *(const bf16x8*)(Qh + ((size_t)sh * Lq + q0 + c) * 32 + g * 8);
    const bf16* Kbase = Kh + (size_t)sh * Lk * 32;
    const bf16* Vbase = Vth + (size_t)sh * 32 * Lk;

    f32x4 o0 = {0, 0, 0, 0}, o1 = {0, 0, 0, 0};
    float l[4] = {0, 0, 0, 0};
    const float scale = 0.17677669529663687f;  // 1/sqrt(32)
    const f32x4 zero = {0, 0, 0, 0};

    int ntiles = Lk >> 5;
    bf16x8 ka = *(const bf16x8*)(Kbase + (size_t)(2 * c) * 32 + g * 8);
    bf16x8 kb = *(const bf16x8*)(Kbase + (size_t)(2 * c + 1) * 32 + g * 8);
    bf16x8 va = *(const bf16x8*)(Vbase + (size_t)c * Lk + g * 8);
    bf16x8 vb = *(const bf16x8*)(Vbase + (size_t)(16 + c) * Lk + g * 8);

    for (int t = 0; t < ntiles; t++) {
        bf16x8 cka = ka, ckb = kb, cva = va, cvb = vb;
        int nk0 = ((t + 1 < ntiles) ? (t + 1) : t) << 5;
        ka = *(const bf16x8*)(Kbase + (size_t)(nk0 + 2 * c) * 32 + g * 8);
        kb = *(const bf16x8*)(Kbase + (size_t)(nk0 + 2 * c + 1) * 32 + g * 8);
        va = *(const bf16x8*)(Vbase + (size_t)c * Lk + nk0 + g * 8);
        vb = *(const bf16x8*)(Vbase + (size_t)(16 + c) * Lk + nk0 + g * 8);

        f32x4 s0 = __builtin_amdgcn_mfma_f32_16x16x32_bf16(aq, cka, zero, 0, 0, 0);
        f32x4 s1 = __builtin_amdgcn_mfma_f32_16x16x32_bf16(aq, ckb, zero, 0, 0, 0);
        int buf = t & 1;
#pragma unroll
        for (int r = 0; r < 4; r++) {
            float e0 = __expf(s0[r] * scale);
            float e1 = __expf(s1[r] * scale);
            l[r] += e0 + e1;
            bf16x2 pk; pk[0] = (bf16)e0; pk[1] = (bf16)e1;
            P_lds[buf][wv][g * 4 + r][c] = pk;
        }
        bf16x8 ap = *(const bf16x8*)&P_lds[buf][wv][c][g * 4];
        o0 = __builtin_amdgcn_mfma_f32_16x16x32_bf16(ap, cva, o0, 0, 0, 0);
        o1 = __builtin_amdgcn_mfma_f32_16x16x32_bf16(ap, cvb, o1, 0, 0, 0);
    }
#pragma unroll
    for (int r = 0; r < 4; r++) {
        float s = l[r];
        s += __shfl_xor(s, 1);
        s += __shfl_xor(s, 2);
        s += __shfl_xor(s, 4);
        s += __shfl_xor(s, 8);
        l[r] = 1.0f / s;
    }
    int h = sh & 3, sb = sh >> 2;
#pragma unroll
    for (int r = 0; r < 4; r++) {
        size_t row = (size_t)sb * Lq + q0 + g * 4 + r;
        ATTh[row * 128 + h * 32 + c] = (bf16)(o0[r] * l[r]);
        ATTh[row * 128 + h * 32 + 16 + c] = (bf16)(o1[r] * l[r]);
    }
}

// ---------------------------------------------------------------------------
extern "C" void kernel_launch(void* const* d_in, const int* in_sizes, int n_in,
                              void* d_out, int out_size, void* d_ws, size_t ws_size,
                              hipStream_t stream) {
    const float* vs       = (const float*)d_in[0];
    const float* semb     = (const float*)d_in[1];
    const float* r5       = (const float*)d_in[2];
    const float* A55      = (const float*)d_in[3];
    const float* bl_bias  = (const float*)d_in[4];
    const float* nl_W1    = (const float*)d_in[5];
    const float* nl_b1    = (const float*)d_in[6];
    const float* nl_W2    = (const float*)d_in[7];
    const float* nl_b2    = (const float*)d_in[8];
    const float* mlp_W1   = (const float*)d_in[9];
    const float* mlp_b1   = (const float*)d_in[10];
    const float* mlp_W2   = (const float*)d_in[11];
    const float* mlp_b2   = (const float*)d_in[12];
    const float* mlp_ln_g = (const float*)d_in[13];
    const float* mlp_ln_b = (const float*)d_in[14];
    const float* enc_qkv_W = (const float*)d_in[15];
    const float* enc_qkv_b = (const float*)d_in[16];
    const float* enc_out_W = (const float*)d_in[17];
    const float* enc_out_b = (const float*)d_in[18];
    const float* enc_ln1_g = (const float*)d_in[19];
    const float* enc_ln1_b = (const float*)d_in[20];
    const float* enc_ff_W1 = (const float*)d_in[21];
    const float* enc_ff_b1 = (const float*)d_in[22];
    const float* enc_ff_W2 = (const float*)d_in[23];
    const float* enc_ff_b2 = (const float*)d_in[24];
    const float* enc_ln2_g = (const float*)d_in[25];
    const float* enc_ln2_b = (const float*)d_in[26];
    const float* ca_Wq = (const float*)d_in[27];
    const float* ca_bq = (const float*)d_in[28];
    const float* ca_Wk = (const float*)d_in[29];
    const float* ca_bk = (const float*)d_in[30];
    const float* ca_Wv = (const float*)d_in[31];
    const float* ca_bv = (const float*)d_in[32];
    const float* ca_Wo = (const float*)d_in[33];
    const float* ca_bo = (const float*)d_in[34];
    const float* ca_ln1_g = (const float*)d_in[35];
    const float* ca_ln1_b = (const float*)d_in[36];
    const float* ca_ff_W1 = (const float*)d_in[37];
    const float* ca_ff_b1 = (const float*)d_in[38];
    const float* ca_ff_W2 = (const float*)d_in[39];
    const float* ca_ff_b2 = (const float*)d_in[40];
    const float* ca_ln2_g = (const float*)d_in[41];
    const float* ca_ln2_b = (const float*)d_in[42];
    float* out = (float*)d_out;

    // Workspace layout (byte offsets, 256-aligned)
    char* base = (char*)d_ws;
    float* b1w   = (float*)(base + 0);          //  32 KB
    float* resid = (float*)(base + 32768);      // 128 KB
    float* X0    = (float*)(base + 163840);     //   4 MB
    float* X1    = (float*)(base + 4358144);    //   4 MB
    char*  QKVr  = base + 8552448;              //  12 MB region
    bf16*  Wpk   = (bf16*) (base + 25329664);   // 1.03 MB
    float* bpk   = (float*)(base + 26411008);   //   1 KB
    bf16*  X0h   = (bf16*) (base + 26412032);   //   2 MB
    bf16*  X1h   = (bf16*) (base + 28509184);   //   2 MB
    bf16*  sembh = (bf16*) (base + 30606336);   //   2 MB
    bf16*  ATTh  = (bf16*) (base + 32703488);   //   2 MB
    bf16*  Qh    = (bf16*)QKVr;                 //   2 MB
    bf16*  Kh    = (bf16*)(QKVr + 2097152);     //   2 MB
    bf16*  Vth   = (bf16*)(QKVr + 4194304);     //   2 MB
    bf16*  CATh  = (bf16*)QKVr;                 //   4 MB (after attn done)
    bf16*  Hh    = (bf16*)(QKVr + 4194304);     //  <=8 MB (after attn done)

    const int NTOK = B_ * T_ * N_;  // 8192

    // Prep (weights + semb cast + bias pack), one launch
    k_prep<<<dim3(6209), dim3(256), 0, stream>>>(
        enc_qkv_W, enc_out_W, enc_ff_W1, enc_ff_W2, ca_Wq, ca_Wk, ca_Wv, ca_Wo,
        ca_ff_W1, ca_ff_W2, mlp_W2, semb, ca_bk, ca_bv, Wpk, sembh, bpk);

    // Residual features + token MLP (mlp gemm fused with gelu+LN+PE+transpose)
    k_b1<<<dim3((B_ * (T_ - 1) + 63) / 64), dim3(64), 0, stream>>>(
        vs, r5, A55, bl_bias, nl_W1, nl_b1, nl_W2, nl_b2, b1w);
    k_resid<<<dim3(NTOK / 64), dim3(64), 0, stream>>>(vs, b1w, resid);
    k_mlp1<<<dim3(NTOK), dim3(128), 0, stream>>>(resid, mlp_W1, mlp_b1, (bf16*)X1h);
    k_gemm_ln<<<dim3(256), dim3(256), 0, stream>>>(
        (bf16*)X1h, Wpk + 524288, mlp_b2, 128, nullptr, mlp_ln_g, mlp_ln_b,
        X0, X0h, 128, nullptr, 1 | 2 | 4);

    // Encoder layers
    for (int i = 0; i < LENC_; i++) {
        k_gemm<<<dim3(3072), dim3(256), 0, stream>>>(
            X0h, Wpk + i * 49152, enc_qkv_b + i * 384, nullptr, nullptr,
            Qh, Kh, Vth, NTOK, 384, 128, 0, 1);
        k_mattn<<<dim3(512), dim3(256), 0, stream>>>(Qh, Kh, Vth, ATTh, 256, 256);
        k_gemm_ln<<<dim3(256), dim3(256), 0, stream>>>(
            ATTh, Wpk + 98304 + i * 16384, enc_out_b + i * 128, 128, X0,
            enc_ln1_g + i * 128, enc_ln1_b + i * 128, X1, X1h, 128, nullptr, 0);
        k_gemm<<<dim3(2048), dim3(256), 0, stream>>>(
            X1h, Wpk + 131072 + i * 32768, enc_ff_b1 + i * 256, nullptr, Hh,
            nullptr, nullptr, nullptr, NTOK, 256, 128, 1, 0);
        k_gemm_ln<<<dim3(256), dim3(256), 0, stream>>>(
            Hh, Wpk + 196608 + i * 32768, enc_ff_b2 + i * 128, 256, X1,
            enc_ln2_g + i * 128, enc_ln2_b + i * 128, X0, X0h, 128, nullptr, 0);
    }

    // Cross-attention (NSH = 16, Lq = Lk = 2048)
    k_gemm<<<dim3(1024), dim3(256), 0, stream>>>(
        sembh, Wpk + 262144, ca_bq, nullptr, nullptr, Qh, nullptr, nullptr,
        NTOK, 128, 128, 0, 2);
    k_gemm<<<dim3(2048), dim3(256), 0, stream>>>(
        X0h, Wpk + 278528, bpk, nullptr, nullptr, nullptr, Kh, Vth,
        NTOK, 256, 128, 0, 3);
    k_mattn<<<dim3(16 * 32), dim3(256), 0, stream>>>(Qh, Kh, Vth, ATTh, 2048, 2048);
    // out-proj + residual(semb) + LN -> X1 fp32, CATh[:, :128] bf16 + cat fill
    k_gemm_ln<<<dim3(256), dim3(256), 0, stream>>>(
        ATTh, Wpk + 311296, ca_bo, 128, semb, ca_ln1_g, ca_ln1_b,
        X1, CATh, 256, X0h, 0);
    k_gemm<<<dim3(4096), dim3(256), 0, stream>>>(
        CATh, Wpk + 327680, ca_ff_b1, nullptr, Hh, nullptr, nullptr, nullptr,
        NTOK, 512, 256, 1, 0);
    k_gemm_ln<<<dim3(256), dim3(256), 0, stream>>>(
        Hh, Wpk + 458752, ca_ff_b2, 512, X1, ca_ln2_g, ca_ln2_b,
        out, nullptr, 128, nullptr, 0);
}